// Round 3
// baseline (927.213 us; speedup 1.0000x reference)
//
#include <hip/hip_runtime.h>
#include <stdint.h>

typedef unsigned short u16;
typedef __attribute__((ext_vector_type(8))) short short8;
typedef __attribute__((ext_vector_type(4))) float floatx4;

#define DEVFN static __device__ __forceinline__

DEVFN float bf2f(u16 u) { unsigned int x = ((unsigned int)u) << 16; float f; __builtin_memcpy(&f, &x, 4); return f; }
DEVFN u16 f2bf(float f) { unsigned int x; __builtin_memcpy(&x, &f, 4); x = (x + 0x7FFFu + ((x >> 16) & 1u)) >> 16; return (u16)x; }
DEVFN float san(float v) { return (v == v) ? v : 0.0f; }

static constexpr int BB = 2048;
static constexpr int NTAIL = 20000;
static constexpr int EE = 512;
static constexpr int CC = 128;

// ---------------------------------------------------------------------------
// NT GEMM: C[M,N] = A[M,K] * B[N,K]^T (+bias fp32) (relu); A,B bf16, fp32 acc.
// mfma_f32_16x16x32_bf16. A-frag: lane holds A[m0+mt*16+(lane&15)][k+(lane>>4)*8+j]
// B-frag identical on B[N,K]. C/D: col=lane&15, row=(lane>>4)*4+reg.
// lda = A row stride (elements). B row stride = K.
// FUSEX: A[row,k] = rs[row,k>>7] * ha[row,k&127] built on the fly (A, lda unused).
// ---------------------------------------------------------------------------
template<int MT, int NT, bool RELU, bool BIAS, bool OUTBF, bool ATOMIC, bool FUSEX>
__global__ __launch_bounds__(64)
void gemm_nt(const u16* __restrict__ A, const u16* __restrict__ Bm,
             void* __restrict__ Cout, const float* __restrict__ bias,
             const u16* __restrict__ rsp, const u16* __restrict__ hap,
             int M, int N, int K, int lda, int klen)
{
    const int lane = threadIdx.x;
    const int r = lane & 15, q = lane >> 4;
    const int m0 = blockIdx.x * (MT * 16);
    const int n0 = blockIdx.y * (NT * 16);
    int k0 = 0, kend = K;
    if (ATOMIC) { k0 = blockIdx.z * klen; kend = k0 + klen; }

    int arow[MT];
    size_t abase[MT];
    size_t bbase[NT];
#pragma unroll
    for (int mt = 0; mt < MT; ++mt) {
        int row = m0 + mt * 16 + r; if (row > M - 1) row = M - 1;
        arow[mt] = row;
        abase[mt] = (size_t)row * (size_t)lda;
    }
#pragma unroll
    for (int nt = 0; nt < NT; ++nt) {
        int row = n0 + nt * 16 + r; if (row > N - 1) row = N - 1;
        bbase[nt] = (size_t)row * (size_t)K;
    }

    floatx4 acc[MT][NT];
#pragma unroll
    for (int mt = 0; mt < MT; ++mt)
#pragma unroll
        for (int nt = 0; nt < NT; ++nt) acc[mt][nt] = (floatx4)0.0f;

    for (int k = k0; k < kend; k += 32) {
        const int ko = k + q * 8;
        short8 af[MT], bfr[NT];
        if (FUSEX) {
            const int e = ko >> 7, c0 = ko & 127;
#pragma unroll
            for (int mt = 0; mt < MT; ++mt) {
                const float rsv = bf2f(rsp[arow[mt] * 128 + e]);
                short8 hv = *reinterpret_cast<const short8*>(hap + arow[mt] * 128 + c0);
                short8 t;
#pragma unroll
                for (int j = 0; j < 8; ++j) t[j] = (short)f2bf(rsv * bf2f((u16)hv[j]));
                af[mt] = t;
            }
        } else {
#pragma unroll
            for (int mt = 0; mt < MT; ++mt)
                af[mt] = *reinterpret_cast<const short8*>(A + abase[mt] + ko);
        }
#pragma unroll
        for (int nt = 0; nt < NT; ++nt)
            bfr[nt] = *reinterpret_cast<const short8*>(Bm + bbase[nt] + ko);
#pragma unroll
        for (int mt = 0; mt < MT; ++mt)
#pragma unroll
            for (int nt = 0; nt < NT; ++nt)
                acc[mt][nt] = __builtin_amdgcn_mfma_f32_16x16x32_bf16(af[mt], bfr[nt], acc[mt][nt], 0, 0, 0);
    }

#pragma unroll
    for (int nt = 0; nt < NT; ++nt) {
        const int col = n0 + nt * 16 + r;
        if (col >= N) continue;
        float bv = 0.0f;
        if (BIAS) bv = san(bias[col]);
#pragma unroll
        for (int mt = 0; mt < MT; ++mt) {
#pragma unroll
            for (int rr = 0; rr < 4; ++rr) {
                const int row = m0 + mt * 16 + q * 4 + rr;
                if (row >= M) continue;
                float v = acc[mt][nt][rr] + bv;
                if (RELU) v = fmaxf(v, 0.0f);
                const size_t idx = (size_t)row * (size_t)N + col;
                if (ATOMIC)      atomicAdd((float*)Cout + idx, v);
                else if (OUTBF)  ((u16*)Cout)[idx] = f2bf(v);
                else             ((float*)Cout)[idx] = v;
            }
        }
    }
}

// fp32 -> bf16 elementwise cast (NaN-sanitized)
__global__ void cast_f32_bf16(const float* __restrict__ in, u16* __restrict__ out, int n)
{
    int id = blockIdx.x * 256 + threadIdx.x;
    if (id < n) out[id] = f2bf(san(in[id]));
}

// fp32 transpose+cast: in[R,C] fp32 -> out[C,R] bf16
__global__ void transpose_f32_bf16(const float* __restrict__ in, u16* __restrict__ out, int R, int C)
{
    __shared__ float tile[32][33];
    int c0 = blockIdx.x * 32, r0 = blockIdx.y * 32;
    int tx = threadIdx.x, ty = threadIdx.y;
#pragma unroll
    for (int i = 0; i < 32; i += 8) {
        int rr = r0 + ty + i, cc = c0 + tx;
        if (rr < R && cc < C) tile[ty + i][tx] = in[(size_t)rr * C + cc];
    }
    __syncthreads();
#pragma unroll
    for (int i = 0; i < 32; i += 8) {
        int orow = c0 + ty + i, ocol = r0 + tx;
        if (orow < C && ocol < R) out[(size_t)orow * R + ocol] = f2bf(san(tile[tx][ty + i]));
    }
}

// concat [head | relation] fp32 -> hr_in [B,1024] bf16
__global__ void concat_hr(const float* __restrict__ h, const float* __restrict__ r, u16* __restrict__ out)
{
    int id = blockIdx.x * 256 + threadIdx.x;
    int b = id >> 10, j = id & 1023;
    float v = (j < 512) ? h[(b << 9) + j] : r[(b << 9) + j - 512];
    out[id] = f2bf(san(v));
}

// BatchNorm batch stats; X [R,128] fp32 -> mean[128], rstd[128]
__global__ __launch_bounds__(256) void bn_stats(const float* __restrict__ X, int R,
                                                float* __restrict__ mean, float* __restrict__ rstd)
{
    __shared__ float ss[256], sq[256];
    int c = blockIdx.x, t = threadIdx.x;
    float s = 0.f, s2 = 0.f;
    for (int rr = t; rr < R; rr += 256) { float v = X[(size_t)rr * 128 + c]; s += v; s2 += v * v; }
    ss[t] = s; sq[t] = s2; __syncthreads();
    for (int off = 128; off > 0; off >>= 1) {
        if (t < off) { ss[t] += ss[t + off]; sq[t] += sq[t + off]; }
        __syncthreads();
    }
    if (t == 0) {
        float m = ss[0] / R;
        float var = fmaxf(sq[0] / R - m * m, 0.0f);
        mean[c] = m;
        rstd[c] = 1.0f / sqrtf(var + 1e-5f);
    }
}

// y = g*(x-m)*rstd + b, g/b fp32, bf16 out
__global__ void bn_apply(const float* __restrict__ X, const float* __restrict__ mean,
                         const float* __restrict__ rstd, const float* __restrict__ g,
                         const float* __restrict__ b, u16* __restrict__ out, int n)
{
    int id = blockIdx.x * 256 + threadIdx.x;
    if (id >= n) return;
    int c = id & 127;
    float v = (X[id] - mean[c]) * rstd[c] * san(g[c]) + san(b[c]);
    out[id] = f2bf(v);
}

__global__ void zero_f32(float* __restrict__ p, int n)
{
    int id = blockIdx.x * 256 + threadIdx.x;
    if (id < n) p[id] = 0.0f;
}

// soft top-k: per row of 128 fp32, thr = 10th largest, out = sigmoid((x-thr)/0.5)*x (bf16)
__global__ __launch_bounds__(64) void soft_topk(const float* __restrict__ X, u16* __restrict__ out)
{
    int row = blockIdx.x, lane = threadIdx.x;
    const float* x = X + (size_t)row * 128;
    float v0 = x[lane], v1 = x[lane + 64];
    float w0 = v0, w1 = v1;
    float thr = 0.f;
    for (int it = 0; it < 10; ++it) {
        float m = fmaxf(w0, w1);
#pragma unroll
        for (int off = 32; off > 0; off >>= 1) m = fmaxf(m, __shfl_xor(m, off));
        if (it == 9) { thr = m; break; }
        unsigned long long msk = __ballot((w0 == m) || (w1 == m));
        if (msk) {
            int first = (int)__builtin_ctzll(msk);
            if (lane == first) {
                if (w0 == m) w0 = -__builtin_inff(); else w1 = -__builtin_inff();
            }
        }
    }
    float z0 = 1.f / (1.f + expf(-(v0 - thr) * 2.f));
    float z1 = 1.f / (1.f + expf(-(v1 - thr) * 2.f));
    out[(size_t)row * 128 + lane]      = f2bf(z0 * v0);
    out[(size_t)row * 128 + lane + 64] = f2bf(z1 * v1);
}

// inter[b,d] = sum_c hrm[b,c] * tanh(codebook[rel[b],c,d]) ; codebook fp32
__global__ __launch_bounds__(128) void inter_kernel(const u16* __restrict__ hrm,
                                                    const float* __restrict__ codebook,
                                                    const int* __restrict__ relidx,
                                                    u16* __restrict__ out)
{
    int b = blockIdx.x, d = threadIdx.x;
    int rel = relidx[b];
    const float* cb = codebook + (size_t)rel * (128 * 128);
    const u16* hr = hrm + (size_t)b * 128;
    float s = 0.f;
    for (int c = 0; c < 128; ++c)
        s += bf2f(hr[c]) * tanhf(san(cb[c * 128 + d]));
    out[(size_t)b * 128 + d] = f2bf(s);
}

// ---------------------------------------------------------------------------
extern "C" void kernel_launch(void* const* d_in, const int* in_sizes, int n_in,
                              void* d_out, int out_size, void* d_ws, size_t ws_size,
                              hipStream_t stream)
{
    (void)in_sizes; (void)n_in; (void)out_size;

    const float* head    = (const float*)d_in[0];
    const float* relv    = (const float*)d_in[1];
    const int*   relidx  = (const int*)d_in[2];
    const float* tail    = (const float*)d_in[3];
    const float* codebook= (const float*)d_in[5];
    const float* core    = (const float*)d_in[6];
    const float* hsw1 = (const float*)d_in[7],  *hsb1 = (const float*)d_in[8];
    const float* hsw2 = (const float*)d_in[9],  *hsb2 = (const float*)d_in[10];
    const float* rsw1 = (const float*)d_in[11], *rsb1 = (const float*)d_in[12];
    const float* rsw2 = (const float*)d_in[13], *rsb2 = (const float*)d_in[14];
    const float* tsw1 = (const float*)d_in[15], *tsb1 = (const float*)d_in[16];
    const float* tsw2 = (const float*)d_in[17], *tsb2 = (const float*)d_in[18];
    const float* bn0g = (const float*)d_in[19], *bn0b = (const float*)d_in[20];
    const float* bn1g = (const float*)d_in[21], *bn1b = (const float*)d_in[22];
    const float* hrw1 = (const float*)d_in[23], *hrb1 = (const float*)d_in[24];
    const float* hrw2 = (const float*)d_in[25], *hrb2 = (const float*)d_in[26];
    const float* hrw3 = (const float*)d_in[27], *hrb3 = (const float*)d_in[28];
    const float* taw1 = (const float*)d_in[29], *tab1 = (const float*)d_in[30];
    const float* taw2 = (const float*)d_in[31], *tab2 = (const float*)d_in[32];

    float* out_tucker = (float*)d_out;
    float* out_poss   = out_tucker + (size_t)BB * NTAIL;

    // ---- workspace layout (~60 MB) ----
    char* ws = (char*)d_ws;
    size_t off = 0;
    auto alloc = [&](size_t bytes) -> char* {
        char* p = ws + off;
        off += (bytes + 255) & ~(size_t)255;
        return p;
    };

    float* hs_f   = (float*)alloc((size_t)BB * CC * 4);
    float* hra_f  = (float*)alloc((size_t)BB * CC * 4);
    float* Wm_pre = (float*)alloc((size_t)BB * CC * 4);
    float* mean0  = (float*)alloc(128 * 4);
    float* rstd0  = (float*)alloc(128 * 4);
    float* mean1  = (float*)alloc(128 * 4);
    float* rstd1  = (float*)alloc(128 * 4);

    u16* t_hid   = (u16*)alloc((size_t)NTAIL * EE * 2);   // [20000,512]
    u16* hr_in   = (u16*)alloc((size_t)BB * 1024 * 2);    // [2048,1024]; later tam (needs next region too)
    u16* h_hid   = (u16*)alloc((size_t)BB * EE * 2);      // [2048,512]; later h1|h2; later tam tail
    u16* h1      = h_hid;                                  // [2048,256]
    u16* h2      = h_hid + (size_t)BB * 256;               // [2048,256]
    u16* tam_bf  = hr_in;                                  // [20000,128] = 5.12MB < 6MB (hr_in+h_hid)
    u16* ts_bf   = (u16*)alloc((size_t)NTAIL * CC * 2);   // [20000,128]
    u16* tail_bf = (u16*)alloc((size_t)NTAIL * EE * 2);   // [20000,512]; later ta_f (fp32 [20000,128])
    float* ta_f  = (float*)tail_bf;                        // 10.24MB <= 20.48MB
    u16* rs_bf   = (u16*)alloc((size_t)BB * CC * 2);
    u16* ha_bf   = (u16*)alloc((size_t)BB * CC * 2);
    u16* Wm_bf   = (u16*)alloc((size_t)BB * CC * 2);
    u16* hrm_bf  = (u16*)alloc((size_t)BB * CC * 2);
    u16* inter_bf= (u16*)alloc((size_t)BB * CC * 2);

    u16* hsw1t = (u16*)alloc((size_t)EE * EE * 2);
    u16* hsw2t = (u16*)alloc((size_t)CC * EE * 2);
    u16* rsw1t = (u16*)alloc((size_t)EE * EE * 2);
    u16* rsw2t = (u16*)alloc((size_t)CC * EE * 2);
    u16* tsw1t = (u16*)alloc((size_t)EE * EE * 2);
    u16* tsw2t = (u16*)alloc((size_t)CC * EE * 2);
    u16* taw1t = (u16*)alloc((size_t)EE * EE * 2);
    u16* taw2t = (u16*)alloc((size_t)CC * EE * 2);
    u16* hrw1t = (u16*)alloc((size_t)256 * 1024 * 2);
    u16* hrw2t = (u16*)alloc((size_t)256 * 256 * 2);
    u16* hrw3t = (u16*)alloc((size_t)128 * 256 * 2);
    u16* core_t = (u16*)alloc((size_t)CC * 16384 * 2);

    if (off > ws_size) return;  // diagnostic: zero output (absmax==stub value) => ws too small

    // ---- weight transposes + casts (fp32 [R,C] -> bf16 [C,R]) ----
    auto T = [&](const float* in, u16* outp, int R, int Cc) {
        dim3 g((Cc + 31) / 32, (R + 31) / 32), b(32, 8);
        transpose_f32_bf16<<<g, b, 0, stream>>>(in, outp, R, Cc);
    };
    T(hsw1, hsw1t, EE, EE);   T(hsw2, hsw2t, EE, CC);
    T(rsw1, rsw1t, EE, EE);   T(rsw2, rsw2t, EE, CC);
    T(tsw1, tsw1t, EE, EE);   T(tsw2, tsw2t, EE, CC);
    T(taw1, taw1t, EE, EE);   T(taw2, taw2t, EE, CC);
    T(hrw1, hrw1t, 2 * EE, 2 * CC);
    T(hrw2, hrw2t, 2 * CC, 2 * CC);
    T(hrw3, hrw3t, 2 * CC, CC);
    T(core, core_t, CC * CC, CC);

    concat_hr<<<(BB * 1024) / 256, 256, 0, stream>>>(head, relv, hr_in);
    cast_f32_bf16<<<(NTAIL * EE) / 256, 256, 0, stream>>>(tail, tail_bf, NTAIL * EE);

    // ---- MLPs (head/relation read slices of hr_in, lda=1024) ----
    gemm_nt<2, 2, true, true, true, false, false><<<dim3(BB / 32, EE / 32), 64, 0, stream>>>(
        hr_in, hsw1t, h_hid, hsb1, nullptr, nullptr, BB, EE, EE, 1024, 0);
    gemm_nt<2, 2, false, true, false, false, false><<<dim3(BB / 32, CC / 32), 64, 0, stream>>>(
        h_hid, hsw2t, hs_f, hsb2, nullptr, nullptr, BB, CC, EE, EE, 0);
    gemm_nt<2, 2, true, true, true, false, false><<<dim3(BB / 32, EE / 32), 64, 0, stream>>>(
        hr_in + 512, rsw1t, h_hid, rsb1, nullptr, nullptr, BB, EE, EE, 1024, 0);
    gemm_nt<2, 2, false, true, true, false, false><<<dim3(BB / 32, CC / 32), 64, 0, stream>>>(
        h_hid, rsw2t, rs_bf, rsb2, nullptr, nullptr, BB, CC, EE, EE, 0);
    gemm_nt<4, 4, true, true, true, false, false><<<dim3((NTAIL + 63) / 64, EE / 64), 64, 0, stream>>>(
        tail_bf, tsw1t, t_hid, tsb1, nullptr, nullptr, NTAIL, EE, EE, EE, 0);
    gemm_nt<4, 4, false, true, true, false, false><<<dim3((NTAIL + 63) / 64, CC / 64), 64, 0, stream>>>(
        t_hid, tsw2t, ts_bf, tsb2, nullptr, nullptr, NTAIL, CC, EE, EE, 0);
    gemm_nt<4, 4, true, true, true, false, false><<<dim3((NTAIL + 63) / 64, EE / 64), 64, 0, stream>>>(
        tail_bf, taw1t, t_hid, tab1, nullptr, nullptr, NTAIL, EE, EE, EE, 0);
    // ta_f aliases tail_bf (tail_bf dead now)
    gemm_nt<4, 4, false, true, false, false, false><<<dim3((NTAIL + 63) / 64, CC / 64), 64, 0, stream>>>(
        t_hid, taw2t, ta_f, tab2, nullptr, nullptr, NTAIL, CC, EE, EE, 0);
    // hr abstract chain (h1/h2 reuse h_hid; hr_in still live as input here)
    gemm_nt<2, 2, true, true, true, false, false><<<dim3(BB / 32, 256 / 32), 64, 0, stream>>>(
        hr_in, hrw1t, h1, hrb1, nullptr, nullptr, BB, 256, 1024, 1024, 0);
    gemm_nt<2, 2, true, true, true, false, false><<<dim3(BB / 32, 256 / 32), 64, 0, stream>>>(
        h1, hrw2t, h2, hrb2, nullptr, nullptr, BB, 256, 256, 256, 0);
    gemm_nt<2, 2, false, true, false, false, false><<<dim3(BB / 32, CC / 32), 64, 0, stream>>>(
        h2, hrw3t, hra_f, hrb3, nullptr, nullptr, BB, CC, 256, 256, 0);

    // ---- BN0 on hs -> ha (bf16) ----
    bn_stats<<<128, 256, 0, stream>>>(hs_f, BB, mean0, rstd0);
    bn_apply<<<(BB * CC) / 256, 256, 0, stream>>>(hs_f, mean0, rstd0, bn0g, bn0b, ha_bf, BB * CC);

    // ---- Wm_pre = (rs (x) ha) @ core2^T, fused A, split-K fp32 atomics ----
    zero_f32<<<(BB * CC) / 256, 256, 0, stream>>>(Wm_pre, BB * CC);
    gemm_nt<2, 2, false, false, false, true, true><<<dim3(BB / 32, CC / 32, 8), 64, 0, stream>>>(
        nullptr, core_t, Wm_pre, nullptr, rs_bf, ha_bf, BB, CC, 16384, 16384, 16384 / 8);

    // ---- BN1 -> Wm (bf16) ----
    bn_stats<<<128, 256, 0, stream>>>(Wm_pre, BB, mean1, rstd1);
    bn_apply<<<(BB * CC) / 256, 256, 0, stream>>>(Wm_pre, mean1, rstd1, bn1g, bn1b, Wm_bf, BB * CC);

    // ---- tucker_logits = Wm @ ts^T (fp32 out) ----
    gemm_nt<4, 4, false, false, false, false, false><<<dim3(BB / 64, (NTAIL + 63) / 64), 64, 0, stream>>>(
        Wm_bf, ts_bf, out_tucker, nullptr, nullptr, nullptr, BB, NTAIL, CC, CC, 0);

    // ---- soft top-k masks (tam_bf reuses hr_in region — hr_in/h_hid dead) ----
    soft_topk<<<BB, 64, 0, stream>>>(hra_f, hrm_bf);
    soft_topk<<<NTAIL, 64, 0, stream>>>(ta_f, tam_bf);

    // ---- inter = einsum(hrm, tanh(codebook[rel])) ----
    inter_kernel<<<BB, 128, 0, stream>>>(hrm_bf, codebook, relidx, inter_bf);

    // ---- possibility = inter @ tam^T (fp32 out) ----
    gemm_nt<4, 4, false, false, false, false, false><<<dim3(BB / 64, (NTAIL + 63) / 64), 64, 0, stream>>>(
        inter_bf, tam_bf, out_poss, nullptr, nullptr, nullptr, BB, NTAIL, CC, CC, 0);
}